// Round 1
// baseline (189.303 us; speedup 1.0000x reference)
//
#include <hip/hip_runtime.h>
#include <math.h>

constexpr int BN = 4096;   // batch
constexpr int CN = 32;     // classes
constexpr int DN = 2048;   // row length
constexpr int KN = 128;    // K smallest
constexpr int NT = 256;    // threads per block

__global__ void zero_out(float* out) {
    if (threadIdx.x == 0 && blockIdx.x == 0) out[0] = 0.f;
}

__global__ __launch_bounds__(NT) void sparse_loss(
    const float* __restrict__ rho,       // [KN]
    const float* __restrict__ encoded,   // [BN, CN, DN]
    const int* __restrict__ labels,      // [BN]
    float* __restrict__ out)             // [1]
{
    __shared__ float s[DN];
    __shared__ float red[NT];

    const int b   = blockIdx.x;
    const int tid = threadIdx.x;
    const int lbl = labels[b];
    const float* row = encoded + ((size_t)b * CN + (size_t)lbl) * DN;

    // ---- stage row into LDS (coalesced) ----
    #pragma unroll
    for (int t = 0; t < DN / NT; ++t)
        s[tid + t * NT] = row[tid + t * NT];
    __syncthreads();

    // ---- full bitonic sort ascending in LDS ----
    for (int k = 2; k <= DN; k <<= 1) {
        for (int j = k >> 1; j > 0; j >>= 1) {
            #pragma unroll
            for (int t = 0; t < DN / NT; ++t) {
                int i   = tid + t * NT;
                int ixj = i ^ j;
                if (ixj > i) {
                    float a  = s[i];
                    float bb = s[ixj];
                    bool up  = ((i & k) == 0);
                    if ((a > bb) == up) { s[i] = bb; s[ixj] = a; }
                }
            }
            __syncthreads();
        }
    }
    // smallest KN values, sorted ascending, now at s[0..KN-1]

    // ---- logsumexp of rho (shared across rows, recomputed per block: cheap) ----
    float rv = (tid < KN) ? rho[tid] : -INFINITY;
    red[tid] = rv;
    __syncthreads();
    for (int off = NT / 2; off > 0; off >>= 1) {
        if (tid < off) red[tid] = fmaxf(red[tid], red[tid + off]);
        __syncthreads();
    }
    float mrho = red[0];
    __syncthreads();

    red[tid] = (tid < KN) ? expf(rv - mrho) : 0.f;
    __syncthreads();
    for (int off = NT / 2; off > 0; off >>= 1) {
        if (tid < off) red[tid] += red[tid + off];
        __syncthreads();
    }
    float lse_rho = mrho + logf(red[0]);
    __syncthreads();

    // ---- logsumexp of the K smallest (max is s[KN-1] since sorted) ----
    float hv   = (tid < KN) ? s[tid] : 0.f;
    float mhat = s[KN - 1];
    red[tid] = (tid < KN) ? expf(hv - mhat) : 0.f;
    __syncthreads();
    for (int off = NT / 2; off > 0; off >>= 1) {
        if (tid < off) red[tid] += red[tid + off];
        __syncthreads();
    }
    float lse_hat = mhat + logf(red[0]);
    __syncthreads();

    // ---- per-k KL terms, exactly as the reference writes them ----
    float term = 0.f;
    if (tid < KN) {
        float lp = rv - lse_rho;   // negative
        float lq = hv - lse_hat;   // negative
        term = lp * logf(lp / lq)
             + (1.f - lp) * logf((1.f - lp) / (1.f - lq));
    }
    red[tid] = term;
    __syncthreads();
    for (int off = NT / 2; off > 0; off >>= 1) {
        if (tid < off) red[tid] += red[tid + off];
        __syncthreads();
    }
    if (tid == 0) atomicAdd(out, red[0]);
}

extern "C" void kernel_launch(void* const* d_in, const int* in_sizes, int n_in,
                              void* d_out, int out_size, void* d_ws, size_t ws_size,
                              hipStream_t stream) {
    const float* rho     = (const float*)d_in[0];
    const float* encoded = (const float*)d_in[1];
    const int*   labels  = (const int*)d_in[2];
    float*       out     = (float*)d_out;

    zero_out<<<1, 64, 0, stream>>>(out);
    sparse_loss<<<BN, NT, 0, stream>>>(rho, encoded, labels, out);
}

// Round 2
// 83.691 us; speedup vs baseline: 2.2619x; 2.2619x over previous
//
#include <hip/hip_runtime.h>
#include <math.h>

constexpr int BN = 4096;   // batch
constexpr int CN = 32;     // classes
constexpr int DN = 2048;   // row length
constexpr int KN = 128;    // K smallest
constexpr int NT = 256;    // threads per block
constexpr int EPT = DN / NT;  // 8 elements per thread

__global__ void zero_out(float* out) {
    if (threadIdx.x == 0 && blockIdx.x == 0) out[0] = 0.f;
}

// monotonic transform: unsigned order == float order
__device__ __forceinline__ unsigned key_of(float f) {
    unsigned u = __float_as_uint(f);
    return (u & 0x80000000u) ? ~u : (u | 0x80000000u);
}

__global__ __launch_bounds__(NT) void sparse_loss(
    const float* __restrict__ rho,       // [KN]
    const float* __restrict__ encoded,   // [BN, CN, DN]
    const int* __restrict__ labels,      // [BN]
    float* __restrict__ out)             // [1]
{
    __shared__ unsigned hist[256];
    __shared__ unsigned scan[256];
    __shared__ float    sel[KN];
    __shared__ float    red[NT];
    __shared__ unsigned s_pivotbin, s_remk, s_cntLess, s_cntEq;

    const int b   = blockIdx.x;
    const int tid = threadIdx.x;
    const int lbl = labels[b];
    const float* row = encoded + ((size_t)b * CN + (size_t)lbl) * DN;

    // ---- row into registers (coalesced), keys precomputed ----
    float    v[EPT];
    unsigned kk[EPT];
    #pragma unroll
    for (int t = 0; t < EPT; ++t) {
        v[t]  = row[tid + t * NT];
        kk[t] = key_of(v[t]);
    }

    // ---- exact radix select: key of the KN-th smallest ----
    unsigned prefix = 0, pmask = 0, remk = KN;
    for (int shift = 24; shift >= 0; shift -= 8) {
        hist[tid] = 0;            // NT == 256 == bins
        __syncthreads();
        #pragma unroll
        for (int t = 0; t < EPT; ++t) {
            if ((kk[t] & pmask) == prefix)
                atomicAdd(&hist[(kk[t] >> shift) & 0xFFu], 1u);
        }
        __syncthreads();
        // inclusive Hillis-Steele scan over 256 bins
        scan[tid] = hist[tid];
        __syncthreads();
        for (int off = 1; off < 256; off <<= 1) {
            unsigned y = (tid >= off) ? scan[tid - off] : 0u;
            __syncthreads();
            scan[tid] += y;
            __syncthreads();
        }
        unsigned incl = scan[tid];
        unsigned excl = incl - hist[tid];
        if (excl < remk && remk <= incl) {   // exactly one thread true
            s_pivotbin = (unsigned)tid;
            s_remk     = remk - excl;
        }
        __syncthreads();
        prefix |= (s_pivotbin << shift);
        pmask  |= (0xFFu << shift);
        remk    = s_remk;
        __syncthreads();
    }
    const unsigned pivot = prefix;            // exact key of KN-th smallest
    const unsigned nless = KN - remk;         // # strictly below pivot

    // ---- compact the KN winners into sel[] (unsorted) ----
    if (tid == 0) { s_cntLess = 0; s_cntEq = 0; }
    __syncthreads();
    #pragma unroll
    for (int t = 0; t < EPT; ++t) {
        if (kk[t] < pivot) {
            unsigned p = atomicAdd(&s_cntLess, 1u);
            sel[p] = v[t];
        } else if (kk[t] == pivot) {
            unsigned p = atomicAdd(&s_cntEq, 1u);
            if (p < remk) sel[nless + p] = v[t];
        }
    }
    __syncthreads();

    // ---- bitonic sort of 128 elements, ascending ----
    for (int k2 = 2; k2 <= KN; k2 <<= 1) {
        for (int j = k2 >> 1; j > 0; j >>= 1) {
            if (tid < KN) {
                int i = tid, ixj = i ^ j;
                if (ixj > i) {
                    float a  = sel[i];
                    float bb = sel[ixj];
                    bool up  = ((i & k2) == 0);
                    if ((a > bb) == up) { sel[i] = bb; sel[ixj] = a; }
                }
            }
            __syncthreads();
        }
    }

    // ---- logsumexp of rho ----
    float rv = (tid < KN) ? rho[tid] : -INFINITY;
    red[tid] = rv;
    __syncthreads();
    for (int off = NT / 2; off > 0; off >>= 1) {
        if (tid < off) red[tid] = fmaxf(red[tid], red[tid + off]);
        __syncthreads();
    }
    float mrho = red[0];
    __syncthreads();

    red[tid] = (tid < KN) ? expf(rv - mrho) : 0.f;
    __syncthreads();
    for (int off = NT / 2; off > 0; off >>= 1) {
        if (tid < off) red[tid] += red[tid + off];
        __syncthreads();
    }
    float lse_rho = mrho + logf(red[0]);
    __syncthreads();

    // ---- logsumexp of the K smallest (max = sel[KN-1], sorted) ----
    float hv   = (tid < KN) ? sel[tid] : 0.f;
    float mhat = sel[KN - 1];
    red[tid] = (tid < KN) ? expf(hv - mhat) : 0.f;
    __syncthreads();
    for (int off = NT / 2; off > 0; off >>= 1) {
        if (tid < off) red[tid] += red[tid + off];
        __syncthreads();
    }
    float lse_hat = mhat + logf(red[0]);
    __syncthreads();

    // ---- per-k KL terms, exactly as reference ----
    float term = 0.f;
    if (tid < KN) {
        float lp = rv - lse_rho;   // negative
        float lq = hv - lse_hat;   // negative
        term = lp * logf(lp / lq)
             + (1.f - lp) * logf((1.f - lp) / (1.f - lq));
    }
    red[tid] = term;
    __syncthreads();
    for (int off = NT / 2; off > 0; off >>= 1) {
        if (tid < off) red[tid] += red[tid + off];
        __syncthreads();
    }
    if (tid == 0) atomicAdd(out, red[0]);
}

extern "C" void kernel_launch(void* const* d_in, const int* in_sizes, int n_in,
                              void* d_out, int out_size, void* d_ws, size_t ws_size,
                              hipStream_t stream) {
    const float* rho     = (const float*)d_in[0];
    const float* encoded = (const float*)d_in[1];
    const int*   labels  = (const int*)d_in[2];
    float*       out     = (float*)d_out;

    zero_out<<<1, 64, 0, stream>>>(out);
    sparse_loss<<<BN, NT, 0, stream>>>(rho, encoded, labels, out);
}

// Round 3
// 24.462 us; speedup vs baseline: 7.7387x; 3.4213x over previous
//
#include <hip/hip_runtime.h>
#include <math.h>

constexpr int BN  = 4096;   // batch (rows)
constexpr int CN  = 32;     // classes
constexpr int DN  = 2048;   // row length
constexpr int KN  = 128;    // K smallest
constexpr int WPB = 4;      // waves (= rows) per block
constexpr int NT  = 64 * WPB;
constexpr int EPL = DN / 64;  // 32 elements per lane

__global__ void zero_out(float* out) {
    if (threadIdx.x == 0 && blockIdx.x == 0) out[0] = 0.f;
}

// wave-local phase fence: order LDS ops within the wave, stop compiler reordering
__device__ __forceinline__ void wavewait() {
    __builtin_amdgcn_wave_barrier();
    asm volatile("s_waitcnt lgkmcnt(0)" ::: "memory");
    __builtin_amdgcn_wave_barrier();
}

// in-register bitonic sort of 128 floats held as 2 regs/lane (i = r*64 + lane), ascending
__device__ __forceinline__ void sort128(float& x0, float& x1, int lane) {
    #pragma unroll
    for (int k = 2; k <= 128; k <<= 1) {
        #pragma unroll
        for (int j = 64; j >= 1; j >>= 1) {
            if (j > (k >> 1)) continue;
            if (j == 64) {
                // partner is the other register, same lane; up = ((i&128)==0) = true
                float mn = fminf(x0, x1), mx = fmaxf(x0, x1);
                x0 = mn; x1 = mx;
            } else {
                {
                    float o  = __shfl_xor(x0, j);
                    bool up    = ((lane & k) == 0);          // i = lane
                    bool lower = ((lane & j) == 0);
                    x0 = (up == lower) ? fminf(x0, o) : fmaxf(x0, o);
                }
                {
                    int  i   = 64 + lane;
                    float o  = __shfl_xor(x1, j);
                    bool up    = ((i & k) == 0);
                    bool lower = ((i & j) == 0);
                    x1 = (up == lower) ? fminf(x1, o) : fmaxf(x1, o);
                }
            }
        }
    }
}

template <bool USE_WS>
__global__ __launch_bounds__(NT) void sparse_loss(
    const float* __restrict__ rho,       // [KN]
    const float* __restrict__ encoded,   // [BN, CN, DN]
    const int*   __restrict__ labels,    // [BN]
    float*       __restrict__ partials,  // [BN] (USE_WS)
    float*       __restrict__ out)       // [1]  (!USE_WS)
{
    __shared__ unsigned hist[WPB][256];
    __shared__ float    sel [WPB][KN];
    __shared__ float    cand[WPB][KN];
    __shared__ unsigned cnt [WPB][2];    // [0]=less, [1]=eq

    const int tid  = threadIdx.x;
    const int w    = tid >> 6;
    const int lane = tid & 63;
    const int row  = blockIdx.x * WPB + w;
    const int lbl  = labels[row];
    const float* rp = encoded + ((size_t)row * CN + (size_t)lbl) * DN;

    // rho fragment (identical for all rows; L2-resident)
    const float r0 = rho[lane], r1 = rho[lane + 64];

    // ---- load row: 8 x float4 per lane, fully coalesced ----
    float v[EPL];
    #pragma unroll
    for (int t = 0; t < 8; ++t) {
        float4 q = ((const float4*)rp)[t * 64 + lane];
        v[4 * t + 0] = q.x; v[4 * t + 1] = q.y;
        v[4 * t + 2] = q.z; v[4 * t + 3] = q.w;
    }

    // ---- init per-wave LDS ----
    hist[w][lane] = 0; hist[w][lane + 64] = 0;
    hist[w][lane + 128] = 0; hist[w][lane + 192] = 0;
    if (lane < 2) cnt[w][lane] = 0;
    cand[w][lane] = INFINITY; cand[w][lane + 64] = INFINITY;
    wavewait();

    // ---- one histogram pass on fixed-point digit floor(v*256); v in [0,1) so
    //      digit order == value order, and uniform data spreads bins evenly ----
    #pragma unroll
    for (int t = 0; t < EPL; ++t) {
        unsigned d = (unsigned)(v[t] * 256.0f);
        atomicAdd(&hist[w][d], 1u);
    }
    wavewait();

    // ---- scan 256 bins (4 per lane) + locate pivot bin ----
    unsigned h0 = hist[w][4 * lane + 0], h1 = hist[w][4 * lane + 1],
             h2 = hist[w][4 * lane + 2], h3 = hist[w][4 * lane + 3];
    unsigned T = h0 + h1 + h2 + h3;
    unsigned inc = T;
    #pragma unroll
    for (int d = 1; d < 64; d <<= 1) {
        unsigned n = __shfl_up(inc, d);
        if (lane >= d) inc += n;
    }
    unsigned e0 = inc - T, e1 = e0 + h0, e2 = e1 + h1, e3 = e2 + h2;

    int      hit = -1;
    unsigned ex  = 0;
    if (e0 < KN && KN <= e0 + h0) { hit = 4 * lane + 0; ex = e0; }
    if (e1 < KN && KN <= e1 + h1) { hit = 4 * lane + 1; ex = e1; }
    if (e2 < KN && KN <= e2 + h2) { hit = 4 * lane + 2; ex = e2; }
    if (e3 < KN && KN <= e3 + h3) { hit = 4 * lane + 3; ex = e3; }
    unsigned long long m = __ballot(hit >= 0);   // exactly one lane set
    int src = __ffsll((unsigned long long)m) - 1;
    unsigned b1    = (unsigned)__shfl(hit, src);
    unsigned nless = __shfl(ex, src);
    unsigned remk  = KN - nless;                 // how many to take from bin b1

    // ---- compact: definite winners (< b1) and pivot-bin candidates (== b1) ----
    #pragma unroll
    for (int t = 0; t < EPL; ++t) {
        unsigned d = (unsigned)(v[t] * 256.0f);
        if (d < b1) {
            unsigned p = atomicAdd(&cnt[w][0], 1u);
            sel[w][p] = v[t];
        } else if (d == b1) {
            unsigned p = atomicAdd(&cnt[w][1], 1u);
            if (p < (unsigned)KN) cand[w][p] = v[t];   // expected ~8 for uniform data
        }
    }
    wavewait();

    // ---- sort candidates, keep the remk smallest ----
    float c0 = cand[w][lane], c1 = cand[w][lane + 64];
    sort128(c0, c1, lane);
    if ((unsigned)lane < remk)        sel[w][nless + lane]      = c0;
    if ((unsigned)(64 + lane) < remk) sel[w][nless + 64 + lane] = c1;
    wavewait();

    // ---- final sorted K smallest ----
    float x0 = sel[w][lane], x1 = sel[w][lane + 64];
    sort128(x0, x1, lane);

    // ---- lse(rho) ----
    float mr = fmaxf(r0, r1);
    #pragma unroll
    for (int d = 1; d < 64; d <<= 1) mr = fmaxf(mr, __shfl_xor(mr, d));
    float sr = __expf(r0 - mr) + __expf(r1 - mr);
    #pragma unroll
    for (int d = 1; d < 64; d <<= 1) sr += __shfl_xor(sr, d);
    const float lse_rho = mr + __logf(sr);

    // ---- lse(rho_hat): max is the last sorted element ----
    float mh = __shfl(x1, 63);
    float sh = __expf(x0 - mh) + __expf(x1 - mh);
    #pragma unroll
    for (int d = 1; d < 64; d <<= 1) sh += __shfl_xor(sh, d);
    const float lse_hat = mh + __logf(sh);

    // ---- KL terms exactly as the reference writes them ----
    float lp0 = r0 - lse_rho, lq0 = x0 - lse_hat;
    float lp1 = r1 - lse_rho, lq1 = x1 - lse_hat;
    float term =
        lp0 * __logf(__fdividef(lp0, lq0)) +
        (1.f - lp0) * __logf(__fdividef(1.f - lp0, 1.f - lq0)) +
        lp1 * __logf(__fdividef(lp1, lq1)) +
        (1.f - lp1) * __logf(__fdividef(1.f - lp1, 1.f - lq1));
    #pragma unroll
    for (int d = 1; d < 64; d <<= 1) term += __shfl_xor(term, d);

    if (USE_WS) {
        if (lane == 0) partials[row] = term;
    } else {
        if (lane == 0) atomicAdd(out, term);
    }
}

__global__ __launch_bounds__(256) void reduce_partials(
    const float* __restrict__ partials, float* __restrict__ out)
{
    __shared__ float red[256];
    float s = 0.f;
    for (int i = threadIdx.x; i < BN; i += 256) s += partials[i];
    red[threadIdx.x] = s;
    __syncthreads();
    for (int off = 128; off > 0; off >>= 1) {
        if (threadIdx.x < off) red[threadIdx.x] += red[threadIdx.x + off];
        __syncthreads();
    }
    if (threadIdx.x == 0) out[0] = red[0];
}

extern "C" void kernel_launch(void* const* d_in, const int* in_sizes, int n_in,
                              void* d_out, int out_size, void* d_ws, size_t ws_size,
                              hipStream_t stream) {
    const float* rho     = (const float*)d_in[0];
    const float* encoded = (const float*)d_in[1];
    const int*   labels  = (const int*)d_in[2];
    float*       out     = (float*)d_out;

    if (ws_size >= (size_t)BN * sizeof(float)) {
        float* partials = (float*)d_ws;
        sparse_loss<true><<<BN / WPB, NT, 0, stream>>>(rho, encoded, labels, partials, out);
        reduce_partials<<<1, 256, 0, stream>>>(partials, out);
    } else {
        zero_out<<<1, 64, 0, stream>>>(out);
        sparse_loss<false><<<BN / WPB, NT, 0, stream>>>(rho, encoded, labels, nullptr, out);
    }
}